// Round 1
// baseline (505.676 us; speedup 1.0000x reference)
//
#include <hip/hip_runtime.h>

#define EMB 128
#define NATOMS 50000
#define NEDGES 800000

typedef __attribute__((ext_vector_type(8))) short bf16x8;
typedef __attribute__((ext_vector_type(4))) float f32x4;

// ---------- ws layout ----------
// [0, 25.6MB)        h_res  (f32, 50000x128)
// [25.6MB, 51.2MB)   x2     (f32, 50000x128)
// [51.2MB, +320KB)   W      (bf16, 10 slots of 128x128, transposed+swizzled)
// [+4B]              idx-width flag
static const size_t H_RES_OFF = 0;
static const size_t X2_OFF    = (size_t)NATOMS * EMB * 4;                  // 25,600,000
static const size_t W_OFF     = 2 * (size_t)NATOMS * EMB * 4;              // 51,200,000
static const size_t FLAG_OFF  = W_OFF + 10 * 128 * 128 * 2;                // 51,527,680

__device__ __forceinline__ short f2bf(float f) {
  unsigned u = __float_as_uint(f);
  u += 0x7fffu + ((u >> 16) & 1u);   // round-to-nearest-even
  return (short)(u >> 16);
}

__device__ __forceinline__ float ssilu(float x) {
  // ScaledSiLU: x * sigmoid(x) / 0.6
  return x * (1.0f / 0.6f) / (1.0f + __expf(-x));
}

// XOR-swizzled LDS indices: 16B units within each 128-elem row, unit ^= (row&7)
__device__ __forceinline__ int xidx(int row, int k) {   // f32 tile [rows][128]
  return (row << 7) + ((((k >> 2) ^ (row & 7)) << 2) | (k & 3));
}
__device__ __forceinline__ int bidx(int row, int k) {   // bf16 tile [rows][128]
  return (row << 7) + ((((k >> 3) ^ (row & 7)) << 3) | (k & 7));
}

// Linear 32KB global->LDS copy of one pre-swizzled weight slot.
__device__ __forceinline__ void stage_w(const short* __restrict__ src, short* dst) {
  const int wave = threadIdx.x >> 6;
  const int lane = threadIdx.x & 63;
  const char* s = (const char*)src;
  char* d = (char*)dst;
#pragma unroll
  for (int i = 0; i < 8; ++i) {
    const int off = wave * 8192 + i * 1024;
    __builtin_amdgcn_global_load_lds(
        (const __attribute__((address_space(1))) void*)(s + off + lane * 16),
        (__attribute__((address_space(3))) void*)(d + off), 16, 0, 0);
  }
}

// Stage a 64x128 f32 tile (guarded) into swizzled LDS.
__device__ __forceinline__ void stage_x(const float* __restrict__ src, int row0, float* x) {
#pragma unroll
  for (int i = 0; i < 8; ++i) {
    const int c = threadIdx.x + i * 256;   // 0..2047 = 64 rows * 32 units
    const int row = c >> 5, unit = c & 31;
    f32x4 v = {0.f, 0.f, 0.f, 0.f};
    if (row0 + row < NATOMS) v = *(const f32x4*)(src + (size_t)(row0 + row) * EMB + unit * 4);
    *(f32x4*)&x[(row << 7) + ((unit ^ (row & 7)) << 2)] = v;
  }
}

// One 16(rows)x128(cols)xK=128 GEMM stage per wave. acc[8] = 8 col-fragments.
// A layout: row=lane%16, k=8*(lane/16)+b ; B from wT[n][k] ; D: col=lane%16, row=4*(lane/16)+reg
template <bool SRC_BF16>
__device__ __forceinline__ void gemm_stage(const float* xsrc, const short* ysrc,
                                           const short* w, int wr0, int lr, int lh,
                                           f32x4* acc) {
#pragma unroll
  for (int kk = 0; kk < 4; ++kk) {
    const int k0 = kk * 32 + lh * 8;
    const int ra = wr0 + lr;
    bf16x8 a;
    if constexpr (SRC_BF16) {
      a = *(const bf16x8*)&ysrc[bidx(ra, k0)];
    } else {
      f32x4 u0 = *(const f32x4*)&xsrc[xidx(ra, k0)];
      f32x4 u1 = *(const f32x4*)&xsrc[xidx(ra, k0 + 4)];
      a[0] = f2bf(u0[0]); a[1] = f2bf(u0[1]); a[2] = f2bf(u0[2]); a[3] = f2bf(u0[3]);
      a[4] = f2bf(u1[0]); a[5] = f2bf(u1[1]); a[6] = f2bf(u1[2]); a[7] = f2bf(u1[3]);
    }
#pragma unroll
    for (int j0 = 0; j0 < 8; ++j0) {
      bf16x8 b = *(const bf16x8*)&w[bidx(j0 * 16 + lr, k0)];
      acc[j0] = __builtin_amdgcn_mfma_f32_16x16x32_bf16(a, b, acc[j0], 0, 0, 0);
    }
  }
}

// ---------------- K0: weight prep ----------------
// grid = 10*128 (slot, k-row), block = 128 (n). Writes bf16 wT[n][k] swizzled.
__global__ void prep_weights(const float* __restrict__ wbf, const float* __restrict__ wpre,
                             const float* __restrict__ wmlp1, const float* __restrict__ wres,
                             short* __restrict__ W) {
  const int s = blockIdx.x >> 7;
  const int k = blockIdx.x & 127;
  const int n = threadIdx.x;
  const float* src;
  if (s == 0) src = wbf;
  else if (s <= 2) src = wpre + (s - 1) * 16384;
  else if (s == 3) src = wmlp1;
  else src = wres + (s - 4) * 16384;
  const float v = src[k * EMB + n];
  W[s * 16384 + (n << 7) + ((((k >> 3) ^ (n & 7)) << 3) | (k & 7))] = f2bf(v);
}

// ---------------- idx dtype detection ----------------
__global__ void detect_idx(const int* __restrict__ idx, int* __restrict__ flag) {
  if (threadIdx.x == 0 && blockIdx.x == 0) {
    int ornz = 0;
#pragma unroll
    for (int i = 0; i < 64; ++i) ornz |= idx[2 * i + 1];
    *flag = (ornz == 0) ? 1 : 0;   // 1 => int64 (high words all zero)
  }
}

// ---------------- K1: pre-residual ----------------
__global__ __launch_bounds__(256, 2) void atom_pre(const float* __restrict__ h,
                                                   float* __restrict__ h_res,
                                                   const short* __restrict__ W) {
  __shared__ float x_lds[64 * 128];
  __shared__ short y_lds[64 * 128];
  __shared__ short w_lds[128 * 128];
  const int lane = threadIdx.x & 63, wave = threadIdx.x >> 6;
  const int lr = lane & 15, lh = lane >> 4;
  const int row0 = blockIdx.x * 64, wr0 = wave * 16;
  const f32x4 vzero = {0.f, 0.f, 0.f, 0.f};

  stage_x(h, row0, x_lds);
  stage_w(W + 1 * 16384, w_lds);
  __syncthreads();

  f32x4 acc[8];
#pragma unroll
  for (int j = 0; j < 8; ++j) acc[j] = vzero;
  gemm_stage<false>(x_lds, nullptr, w_lds, wr0, lr, lh, acc);
#pragma unroll
  for (int j0 = 0; j0 < 8; ++j0)
#pragma unroll
    for (int j = 0; j < 4; ++j)
      y_lds[bidx(wr0 + lh * 4 + j, j0 * 16 + lr)] = f2bf(ssilu(acc[j0][j]));

  __syncthreads();
  stage_w(W + 2 * 16384, w_lds);
  __syncthreads();

#pragma unroll
  for (int j = 0; j < 8; ++j) acc[j] = vzero;
  gemm_stage<true>(nullptr, y_lds, w_lds, wr0, lr, lh, acc);

#pragma unroll
  for (int j = 0; j < 4; ++j) {
    const int row = wr0 + lh * 4 + j;
    const int ga = row0 + row;
    if (ga < NATOMS) {
#pragma unroll
      for (int j0 = 0; j0 < 8; ++j0) {
        const int col = j0 * 16 + lr;
        h_res[(size_t)ga * EMB + col] =
            (x_lds[xidx(row, col)] + ssilu(acc[j0][j])) * 0.70710678118654752440f;
      }
    }
  }
}

// ---------------- K2: edge GEMM + gather-hadamard + scatter-add ----------------
__global__ __launch_bounds__(256) void edge_kernel(const float* __restrict__ bf,
                                                   const float* __restrict__ h_res,
                                                   const void* __restrict__ idx_s_p,
                                                   const void* __restrict__ idx_t_p,
                                                   const short* __restrict__ W,
                                                   float* __restrict__ x2,
                                                   const int* __restrict__ flag) {
  __shared__ short w_lds[128 * 128];
  __shared__ int is_lds[128];
  __shared__ int it_lds[128];
  const int tid = threadIdx.x, lane = tid & 63, wave = tid >> 6;
  const int lr = lane & 15, lh = lane >> 4;
  const size_t tile = (size_t)blockIdx.x * 128;
  const int f64 = *flag;

  stage_w(W, w_lds);   // slot 0 = w_bf
  if (tid < 128) {
    is_lds[tid] = f64 ? (int)((const long long*)idx_s_p)[tile + tid]
                      : ((const int*)idx_s_p)[tile + tid];
  } else {
    const int t = tid - 128;
    it_lds[t] = f64 ? (int)((const long long*)idx_t_p)[tile + t]
                    : ((const int*)idx_t_p)[tile + t];
  }
  __syncthreads();

  const int e0 = wave * 32;
  const f32x4 vzero = {0.f, 0.f, 0.f, 0.f};
  f32x4 acc[2][8];
#pragma unroll
  for (int rf = 0; rf < 2; ++rf)
#pragma unroll
    for (int j0 = 0; j0 < 8; ++j0) acc[rf][j0] = vzero;

#pragma unroll
  for (int kk = 0; kk < 4; ++kk) {
    const int k0 = kk * 32 + lh * 8;
    bf16x8 a[2];
#pragma unroll
    for (int rf = 0; rf < 2; ++rf) {
      const float* p = bf + (tile + e0 + rf * 16 + lr) * EMB + k0;
      f32x4 u0 = *(const f32x4*)p;
      f32x4 u1 = *(const f32x4*)(p + 4);
      a[rf][0] = f2bf(u0[0]); a[rf][1] = f2bf(u0[1]); a[rf][2] = f2bf(u0[2]); a[rf][3] = f2bf(u0[3]);
      a[rf][4] = f2bf(u1[0]); a[rf][5] = f2bf(u1[1]); a[rf][6] = f2bf(u1[2]); a[rf][7] = f2bf(u1[3]);
    }
#pragma unroll
    for (int j0 = 0; j0 < 8; ++j0) {
      bf16x8 b = *(const bf16x8*)&w_lds[bidx(j0 * 16 + lr, k0)];
      acc[0][j0] = __builtin_amdgcn_mfma_f32_16x16x32_bf16(a[0], b, acc[0][j0], 0, 0, 0);
      acc[1][j0] = __builtin_amdgcn_mfma_f32_16x16x32_bf16(a[1], b, acc[1][j0], 0, 0, 0);
    }
  }

  // epilogue: x = h_res[idx_s] * mlp_bf ; atomic scatter-add into x2[idx_t]
#pragma unroll
  for (int rf = 0; rf < 2; ++rf) {
#pragma unroll
    for (int j = 0; j < 4; ++j) {
      const int el = e0 + rf * 16 + lh * 4 + j;
      const float* hrow = h_res + (size_t)is_lds[el] * EMB;
      float* orow = x2 + (size_t)it_lds[el] * EMB;
#pragma unroll
      for (int j0 = 0; j0 < 8; ++j0) {
        const int col = j0 * 16 + lr;
        atomicAdd(&orow[col], acc[rf][j0][j] * hrow[col]);
      }
    }
  }
}

// ---------------- K3: post MLP (scale -> mlp1+silu -> 3 residual layers) ----------------
__global__ __launch_bounds__(256, 2) void atom_post(const float* __restrict__ x2,
                                                    float* __restrict__ out,
                                                    const short* __restrict__ W,
                                                    const float* __restrict__ scale_sum) {
  __shared__ float x_lds[64 * 128];
  __shared__ short y_lds[64 * 128];
  __shared__ short w_lds[128 * 128];
  const int lane = threadIdx.x & 63, wave = threadIdx.x >> 6;
  const int lr = lane & 15, lh = lane >> 4;
  const int row0 = blockIdx.x * 64, wr0 = wave * 16;
  const float sc = scale_sum[0];
  const f32x4 vzero = {0.f, 0.f, 0.f, 0.f};

  stage_x(x2, row0, x_lds);
  stage_w(W + 3 * 16384, w_lds);   // w_mlp1
  __syncthreads();

  f32x4 acc[8];
#pragma unroll
  for (int j = 0; j < 8; ++j) acc[j] = vzero;
  gemm_stage<false>(x_lds, nullptr, w_lds, wr0, lr, lh, acc);
#pragma unroll
  for (int j0 = 0; j0 < 8; ++j0)
#pragma unroll
    for (int j = 0; j < 4; ++j)
      x_lds[xidx(wr0 + lh * 4 + j, j0 * 16 + lr)] = ssilu(acc[j0][j] * sc);

  for (int L = 0; L < 3; ++L) {
    __syncthreads();
    stage_w(W + (size_t)(4 + 2 * L) * 16384, w_lds);
    __syncthreads();
#pragma unroll
    for (int j = 0; j < 8; ++j) acc[j] = vzero;
    gemm_stage<false>(x_lds, nullptr, w_lds, wr0, lr, lh, acc);
#pragma unroll
    for (int j0 = 0; j0 < 8; ++j0)
#pragma unroll
      for (int j = 0; j < 4; ++j)
        y_lds[bidx(wr0 + lh * 4 + j, j0 * 16 + lr)] = f2bf(ssilu(acc[j0][j]));

    __syncthreads();
    stage_w(W + (size_t)(5 + 2 * L) * 16384, w_lds);
    __syncthreads();
#pragma unroll
    for (int j = 0; j < 8; ++j) acc[j] = vzero;
    gemm_stage<true>(nullptr, y_lds, w_lds, wr0, lr, lh, acc);

    if (L < 2) {
#pragma unroll
      for (int j = 0; j < 4; ++j) {
        const int row = wr0 + lh * 4 + j;
#pragma unroll
        for (int j0 = 0; j0 < 8; ++j0) {
          const int col = j0 * 16 + lr;
          const float xv = x_lds[xidx(row, col)];
          x_lds[xidx(row, col)] = (xv + ssilu(acc[j0][j])) * 0.70710678118654752440f;
        }
      }
    } else {
#pragma unroll
      for (int j = 0; j < 4; ++j) {
        const int row = wr0 + lh * 4 + j;
        const int ga = row0 + row;
        if (ga < NATOMS) {
#pragma unroll
          for (int j0 = 0; j0 < 8; ++j0) {
            const int col = j0 * 16 + lr;
            out[(size_t)ga * EMB + col] =
                (x_lds[xidx(row, col)] + ssilu(acc[j0][j])) * 0.70710678118654752440f;
          }
        }
      }
    }
  }
}

extern "C" void kernel_launch(void* const* d_in, const int* in_sizes, int n_in,
                              void* d_out, int out_size, void* d_ws, size_t ws_size,
                              hipStream_t stream) {
  const float* h        = (const float*)d_in[0];
  const float* bf       = (const float*)d_in[1];
  const void*  idx_s    = d_in[2];
  const void*  idx_t    = d_in[3];
  const float* w_bf     = (const float*)d_in[4];
  const float* w_pre    = (const float*)d_in[5];
  const float* w_mlp1   = (const float*)d_in[6];
  const float* w_res    = (const float*)d_in[7];
  const float* scale    = (const float*)d_in[8];
  float* out = (float*)d_out;

  char* ws = (char*)d_ws;
  float* h_res = (float*)(ws + H_RES_OFF);
  float* x2    = (float*)(ws + X2_OFF);
  short* W     = (short*)(ws + W_OFF);
  int*   flag  = (int*)(ws + FLAG_OFF);

  hipMemsetAsync(x2, 0, (size_t)NATOMS * EMB * 4, stream);
  prep_weights<<<dim3(10 * 128), dim3(128), 0, stream>>>(w_bf, w_pre, w_mlp1, w_res, W);
  detect_idx<<<dim3(1), dim3(64), 0, stream>>>((const int*)idx_s, flag);
  atom_pre<<<dim3((NATOMS + 63) / 64), dim3(256), 0, stream>>>(h, h_res, W);
  edge_kernel<<<dim3(NEDGES / 128), dim3(256), 0, stream>>>(bf, h_res, idx_s, idx_t, W, x2, flag);
  atom_post<<<dim3((NATOMS + 63) / 64), dim3(256), 0, stream>>>(x2, out, W, scale);
}

// Round 2
// 437.175 us; speedup vs baseline: 1.1567x; 1.1567x over previous
//
#include <hip/hip_runtime.h>

#define EMB 128
#define NATOMS 50000
#define NEDGES 800000
#define PADN 50176            // 196 * 256 >= NATOMS

typedef __attribute__((ext_vector_type(8))) short bf16x8;
typedef __attribute__((ext_vector_type(4))) float f32x4;

// ---------- ws layout ----------
static const size_t H_RES_OFF  = 0;                                   // 25.6 MB f32
static const size_t X2_OFF     = (size_t)NATOMS * EMB * 4;            // 25.6 MB f32
static const size_t W_OFF      = 2 * (size_t)NATOMS * EMB * 4;        // 320 KB bf16
static const size_t FLAG_OFF   = W_OFF + 10 * 128 * 128 * 2;          // 4 B
static const size_t COUNTS_OFF = (FLAG_OFF + 4 + 255) & ~(size_t)255; // PADN ints
static const size_t SEG_OFF    = COUNTS_OFF + (size_t)PADN * 4;       // PADN ints
static const size_t CURSOR_OFF = SEG_OFF + (size_t)PADN * 4;          // PADN ints
static const size_t BSUM_OFF   = CURSOR_OFF + (size_t)PADN * 4;       // 256 ints
static const size_t ORDER_OFF  = BSUM_OFF + 1024;                     // NEDGES ints
// total ~55.4 MB

__device__ __forceinline__ short f2bf(float f) {
  unsigned u = __float_as_uint(f);
  u += 0x7fffu + ((u >> 16) & 1u);   // round-to-nearest-even
  return (short)(u >> 16);
}

__device__ __forceinline__ float ssilu(float x) {
  return x * (1.0f / 0.6f) / (1.0f + __expf(-x));
}

// XOR-swizzled LDS indices: 16B units within each 128-elem row, unit ^= (row&7)
__device__ __forceinline__ int xidx(int row, int k) {   // f32 tile [rows][128]
  return (row << 7) + ((((k >> 2) ^ (row & 7)) << 2) | (k & 3));
}
__device__ __forceinline__ int bidx(int row, int k) {   // bf16 tile [rows][128]
  return (row << 7) + ((((k >> 3) ^ (row & 7)) << 3) | (k & 7));
}

// Linear 32KB global->LDS copy of one pre-swizzled weight slot.
__device__ __forceinline__ void stage_w(const short* __restrict__ src, short* dst) {
  const int wave = threadIdx.x >> 6;
  const int lane = threadIdx.x & 63;
  const char* s = (const char*)src;
  char* d = (char*)dst;
#pragma unroll
  for (int i = 0; i < 8; ++i) {
    const int off = wave * 8192 + i * 1024;
    __builtin_amdgcn_global_load_lds(
        (const __attribute__((address_space(1))) void*)(s + off + lane * 16),
        (__attribute__((address_space(3))) void*)(d + off), 16, 0, 0);
  }
}

__device__ __forceinline__ void stage_x(const float* __restrict__ src, int row0, float* x) {
#pragma unroll
  for (int i = 0; i < 8; ++i) {
    const int c = threadIdx.x + i * 256;
    const int row = c >> 5, unit = c & 31;
    f32x4 v = {0.f, 0.f, 0.f, 0.f};
    if (row0 + row < NATOMS) v = *(const f32x4*)(src + (size_t)(row0 + row) * EMB + unit * 4);
    *(f32x4*)&x[(row << 7) + ((unit ^ (row & 7)) << 2)] = v;
  }
}

template <bool SRC_BF16>
__device__ __forceinline__ void gemm_stage(const float* xsrc, const short* ysrc,
                                           const short* w, int wr0, int lr, int lh,
                                           f32x4* acc) {
#pragma unroll
  for (int kk = 0; kk < 4; ++kk) {
    const int k0 = kk * 32 + lh * 8;
    const int ra = wr0 + lr;
    bf16x8 a;
    if constexpr (SRC_BF16) {
      a = *(const bf16x8*)&ysrc[bidx(ra, k0)];
    } else {
      f32x4 u0 = *(const f32x4*)&xsrc[xidx(ra, k0)];
      f32x4 u1 = *(const f32x4*)&xsrc[xidx(ra, k0 + 4)];
      a[0] = f2bf(u0[0]); a[1] = f2bf(u0[1]); a[2] = f2bf(u0[2]); a[3] = f2bf(u0[3]);
      a[4] = f2bf(u1[0]); a[5] = f2bf(u1[1]); a[6] = f2bf(u1[2]); a[7] = f2bf(u1[3]);
    }
#pragma unroll
    for (int j0 = 0; j0 < 8; ++j0) {
      bf16x8 b = *(const bf16x8*)&w[bidx(j0 * 16 + lr, k0)];
      acc[j0] = __builtin_amdgcn_mfma_f32_16x16x32_bf16(a, b, acc[j0], 0, 0, 0);
    }
  }
}

// ---------------- K0: weight prep ----------------
__global__ void prep_weights(const float* __restrict__ wbf, const float* __restrict__ wpre,
                             const float* __restrict__ wmlp1, const float* __restrict__ wres,
                             short* __restrict__ W) {
  const int s = blockIdx.x >> 7;
  const int k = blockIdx.x & 127;
  const int n = threadIdx.x;
  const float* src;
  if (s == 0) src = wbf;
  else if (s <= 2) src = wpre + (s - 1) * 16384;
  else if (s == 3) src = wmlp1;
  else src = wres + (s - 4) * 16384;
  const float v = src[k * EMB + n];
  W[s * 16384 + (n << 7) + ((((k >> 3) ^ (n & 7)) << 3) | (k & 7))] = f2bf(v);
}

// ---------------- idx dtype detection ----------------
__global__ void detect_idx(const int* __restrict__ idx, int* __restrict__ flag) {
  if (threadIdx.x == 0 && blockIdx.x == 0) {
    int ornz = 0;
#pragma unroll
    for (int i = 0; i < 64; ++i) ornz |= idx[2 * i + 1];
    *flag = (ornz == 0) ? 1 : 0;   // 1 => int64
  }
}

__device__ __forceinline__ int load_idx(const void* p, int e, int f64) {
  return f64 ? (int)((const long long*)p)[e] : ((const int*)p)[e];
}

// ---------------- sort pipeline ----------------
__global__ void hist_kernel(const void* __restrict__ idx_t_p, int* __restrict__ counts,
                            const int* __restrict__ flag) {
  const int e = blockIdx.x * 256 + threadIdx.x;
  if (e < NEDGES) atomicAdd(&counts[load_idx(idx_t_p, e, *flag)], 1);
}

__global__ void scan_blocks(const int* __restrict__ counts, int* __restrict__ seg,
                            int* __restrict__ bsum) {
  const int i = blockIdx.x * 256 + threadIdx.x;
  const int lane = threadIdx.x & 63, wave = threadIdx.x >> 6;
  const int v = counts[i];
  int incl = v;
#pragma unroll
  for (int d = 1; d < 64; d <<= 1) {
    int t = __shfl_up(incl, d, 64);
    if (lane >= d) incl += t;
  }
  __shared__ int wtot[4];
  if (lane == 63) wtot[wave] = incl;
  __syncthreads();
  int woff = 0;
  for (int w = 0; w < wave; ++w) woff += wtot[w];
  seg[i] = woff + incl - v;
  if (threadIdx.x == 255) bsum[blockIdx.x] = woff + incl;
}

__global__ void scan_top(int* __restrict__ bsum) {
  const int i = threadIdx.x;
  const int lane = i & 63, wave = i >> 6;
  const int v = (i < 196) ? bsum[i] : 0;
  int incl = v;
#pragma unroll
  for (int d = 1; d < 64; d <<= 1) {
    int t = __shfl_up(incl, d, 64);
    if (lane >= d) incl += t;
  }
  __shared__ int wtot[4];
  if (lane == 63) wtot[wave] = incl;
  __syncthreads();
  int woff = 0;
  for (int w = 0; w < wave; ++w) woff += wtot[w];
  if (i < 196) bsum[i] = woff + incl - v;
}

__global__ void add_off(int* __restrict__ seg, const int* __restrict__ bsum,
                        int* __restrict__ cursor) {
  const int i = blockIdx.x * 256 + threadIdx.x;
  const int s = seg[i] + bsum[blockIdx.x];
  seg[i] = s;
  cursor[i] = s;
}

__global__ void scatter_kernel(const void* __restrict__ idx_t_p, int* __restrict__ cursor,
                               int* __restrict__ order, const int* __restrict__ flag) {
  const int e = blockIdx.x * 256 + threadIdx.x;
  if (e < NEDGES) {
    const int t = load_idx(idx_t_p, e, *flag);
    const int pos = atomicAdd(&cursor[t], 1);
    order[pos] = e;
  }
}

// ---------------- K1: pre-residual ----------------
__global__ __launch_bounds__(256, 2) void atom_pre(const float* __restrict__ h,
                                                   float* __restrict__ h_res,
                                                   const short* __restrict__ W) {
  __shared__ float x_lds[64 * 128];
  __shared__ short y_lds[64 * 128];
  __shared__ short w_lds[128 * 128];
  const int lane = threadIdx.x & 63, wave = threadIdx.x >> 6;
  const int lr = lane & 15, lh = lane >> 4;
  const int row0 = blockIdx.x * 64, wr0 = wave * 16;
  const f32x4 vzero = {0.f, 0.f, 0.f, 0.f};

  stage_x(h, row0, x_lds);
  stage_w(W + 1 * 16384, w_lds);
  __syncthreads();

  f32x4 acc[8];
#pragma unroll
  for (int j = 0; j < 8; ++j) acc[j] = vzero;
  gemm_stage<false>(x_lds, nullptr, w_lds, wr0, lr, lh, acc);
#pragma unroll
  for (int j0 = 0; j0 < 8; ++j0)
#pragma unroll
    for (int j = 0; j < 4; ++j)
      y_lds[bidx(wr0 + lh * 4 + j, j0 * 16 + lr)] = f2bf(ssilu(acc[j0][j]));

  __syncthreads();
  stage_w(W + 2 * 16384, w_lds);
  __syncthreads();

#pragma unroll
  for (int j = 0; j < 8; ++j) acc[j] = vzero;
  gemm_stage<true>(nullptr, y_lds, w_lds, wr0, lr, lh, acc);

#pragma unroll
  for (int j = 0; j < 4; ++j) {
    const int row = wr0 + lh * 4 + j;
    const int ga = row0 + row;
    if (ga < NATOMS) {
#pragma unroll
      for (int j0 = 0; j0 < 8; ++j0) {
        const int col = j0 * 16 + lr;
        h_res[(size_t)ga * EMB + col] =
            (x_lds[xidx(row, col)] + ssilu(acc[j0][j])) * 0.70710678118654752440f;
      }
    }
  }
}

// ---------------- K2: atom-centric edge GEMM + hadamard + segment-sum ----------------
__global__ __launch_bounds__(256) void edge_atom(const float* __restrict__ bf,
                                                 const float* __restrict__ h_res,
                                                 const void* __restrict__ idx_s_p,
                                                 const int* __restrict__ seg,
                                                 const int* __restrict__ order,
                                                 const short* __restrict__ W,
                                                 float* __restrict__ x2,
                                                 const int* __restrict__ flag) {
  __shared__ short w_lds[128 * 128];
  const int lane = threadIdx.x & 63, wave = threadIdx.x >> 6;
  const int lr = lane & 15, lh = lane >> 4;
  const int f64 = *flag;

  stage_w(W, w_lds);   // slot 0 = w_bf
  __syncthreads();

  const int gwid = blockIdx.x * 4 + wave;
  const int nw = gridDim.x * 4;
  const f32x4 vzero = {0.f, 0.f, 0.f, 0.f};

  for (int t = gwid; t < NATOMS; t += nw) {
    const int s0 = seg[t], s1 = seg[t + 1];
    float psum[8] = {0.f, 0.f, 0.f, 0.f, 0.f, 0.f, 0.f, 0.f};

    for (int c0 = s0; c0 < s1; c0 += 16) {
      const int rem = s1 - c0;                 // wave-uniform
      int e = 0, is = 0;
      const bool rowok = (lr < rem);
      if (rowok) {
        e = order[c0 + lr];
        is = load_idx(idx_s_p, e, f64);
      }
      f32x4 acc[8];
#pragma unroll
      for (int j = 0; j < 8; ++j) acc[j] = vzero;

#pragma unroll
      for (int kk = 0; kk < 4; ++kk) {
        bf16x8 a = {0, 0, 0, 0, 0, 0, 0, 0};
        if (rowok) {
          const float* p = bf + (size_t)e * EMB + kk * 32 + lh * 8;
          f32x4 u0 = *(const f32x4*)p;
          f32x4 u1 = *(const f32x4*)(p + 4);
          a[0] = f2bf(u0[0]); a[1] = f2bf(u0[1]); a[2] = f2bf(u0[2]); a[3] = f2bf(u0[3]);
          a[4] = f2bf(u1[0]); a[5] = f2bf(u1[1]); a[6] = f2bf(u1[2]); a[7] = f2bf(u1[3]);
        }
#pragma unroll
        for (int j0 = 0; j0 < 8; ++j0) {
          bf16x8 b = *(const bf16x8*)&w_lds[bidx(j0 * 16 + lr, kk * 32 + lh * 8)];
          acc[j0] = __builtin_amdgcn_mfma_f32_16x16x32_bf16(a, b, acc[j0], 0, 0, 0);
        }
      }

      // Hadamard with h_res[idx_s], accumulate row-sums per (col) into psum
#pragma unroll
      for (int j = 0; j < 4; ++j) {
        const int row = 4 * lh + j;            // D row held in this lane's reg j
        const int src = (lh << 4) | row;       // lane in same lh-group with lr == row
        const int isj = __shfl(is, src, 64);
        if (row < rem) {
          const float* hrow = h_res + (size_t)isj * EMB;
#pragma unroll
          for (int j0 = 0; j0 < 8; ++j0)
            psum[j0] += acc[j0][j] * hrow[j0 * 16 + lr];
        }
      }
    }

    // reduce across lh groups: lanes 0..15 end up with col sums
#pragma unroll
    for (int j0 = 0; j0 < 8; ++j0) {
      float r = psum[j0];
      r += __shfl_xor(r, 16, 64);
      r += __shfl_xor(r, 32, 64);
      psum[j0] = r;
    }
    if (lane < 16) {
#pragma unroll
      for (int j0 = 0; j0 < 8; ++j0)
        x2[(size_t)t * EMB + j0 * 16 + lane] = psum[j0];
    }
  }
}

// ---------------- K3: post MLP ----------------
__global__ __launch_bounds__(256, 2) void atom_post(const float* __restrict__ x2,
                                                    float* __restrict__ out,
                                                    const short* __restrict__ W,
                                                    const float* __restrict__ scale_sum) {
  __shared__ float x_lds[64 * 128];
  __shared__ short y_lds[64 * 128];
  __shared__ short w_lds[128 * 128];
  const int lane = threadIdx.x & 63, wave = threadIdx.x >> 6;
  const int lr = lane & 15, lh = lane >> 4;
  const int row0 = blockIdx.x * 64, wr0 = wave * 16;
  const float sc = scale_sum[0];
  const f32x4 vzero = {0.f, 0.f, 0.f, 0.f};

  stage_x(x2, row0, x_lds);
  stage_w(W + 3 * 16384, w_lds);   // w_mlp1
  __syncthreads();

  f32x4 acc[8];
#pragma unroll
  for (int j = 0; j < 8; ++j) acc[j] = vzero;
  gemm_stage<false>(x_lds, nullptr, w_lds, wr0, lr, lh, acc);
#pragma unroll
  for (int j0 = 0; j0 < 8; ++j0)
#pragma unroll
    for (int j = 0; j < 4; ++j)
      x_lds[xidx(wr0 + lh * 4 + j, j0 * 16 + lr)] = ssilu(acc[j0][j] * sc);

  for (int L = 0; L < 3; ++L) {
    __syncthreads();
    stage_w(W + (size_t)(4 + 2 * L) * 16384, w_lds);
    __syncthreads();
#pragma unroll
    for (int j = 0; j < 8; ++j) acc[j] = vzero;
    gemm_stage<false>(x_lds, nullptr, w_lds, wr0, lr, lh, acc);
#pragma unroll
    for (int j0 = 0; j0 < 8; ++j0)
#pragma unroll
      for (int j = 0; j < 4; ++j)
        y_lds[bidx(wr0 + lh * 4 + j, j0 * 16 + lr)] = f2bf(ssilu(acc[j0][j]));

    __syncthreads();
    stage_w(W + (size_t)(5 + 2 * L) * 16384, w_lds);
    __syncthreads();
#pragma unroll
    for (int j = 0; j < 8; ++j) acc[j] = vzero;
    gemm_stage<true>(nullptr, y_lds, w_lds, wr0, lr, lh, acc);

    if (L < 2) {
#pragma unroll
      for (int j = 0; j < 4; ++j) {
        const int row = wr0 + lh * 4 + j;
#pragma unroll
        for (int j0 = 0; j0 < 8; ++j0) {
          const int col = j0 * 16 + lr;
          const float xv = x_lds[xidx(row, col)];
          x_lds[xidx(row, col)] = (xv + ssilu(acc[j0][j])) * 0.70710678118654752440f;
        }
      }
    } else {
#pragma unroll
      for (int j = 0; j < 4; ++j) {
        const int row = wr0 + lh * 4 + j;
        const int ga = row0 + row;
        if (ga < NATOMS) {
#pragma unroll
          for (int j0 = 0; j0 < 8; ++j0) {
            const int col = j0 * 16 + lr;
            out[(size_t)ga * EMB + col] =
                (x_lds[xidx(row, col)] + ssilu(acc[j0][j])) * 0.70710678118654752440f;
          }
        }
      }
    }
  }
}

extern "C" void kernel_launch(void* const* d_in, const int* in_sizes, int n_in,
                              void* d_out, int out_size, void* d_ws, size_t ws_size,
                              hipStream_t stream) {
  const float* h      = (const float*)d_in[0];
  const float* bf     = (const float*)d_in[1];
  const void*  idx_s  = d_in[2];
  const void*  idx_t  = d_in[3];
  const float* w_bf   = (const float*)d_in[4];
  const float* w_pre  = (const float*)d_in[5];
  const float* w_mlp1 = (const float*)d_in[6];
  const float* w_res  = (const float*)d_in[7];
  const float* scale  = (const float*)d_in[8];
  float* out = (float*)d_out;

  char* ws = (char*)d_ws;
  float* h_res  = (float*)(ws + H_RES_OFF);
  float* x2     = (float*)(ws + X2_OFF);
  short* W      = (short*)(ws + W_OFF);
  int*   flag   = (int*)(ws + FLAG_OFF);
  int*   counts = (int*)(ws + COUNTS_OFF);
  int*   segp   = (int*)(ws + SEG_OFF);
  int*   cursor = (int*)(ws + CURSOR_OFF);
  int*   bsum   = (int*)(ws + BSUM_OFF);
  int*   order  = (int*)(ws + ORDER_OFF);

  hipMemsetAsync(counts, 0, (size_t)PADN * 4, stream);
  prep_weights<<<dim3(10 * 128), dim3(128), 0, stream>>>(w_bf, w_pre, w_mlp1, w_res, W);
  detect_idx<<<dim3(1), dim3(64), 0, stream>>>((const int*)idx_s, flag);

  hist_kernel<<<dim3(NEDGES / 256), dim3(256), 0, stream>>>(idx_t, counts, flag);
  scan_blocks<<<dim3(PADN / 256), dim3(256), 0, stream>>>(counts, segp, bsum);
  scan_top<<<dim3(1), dim3(256), 0, stream>>>(bsum);
  add_off<<<dim3(PADN / 256), dim3(256), 0, stream>>>(segp, bsum, cursor);
  scatter_kernel<<<dim3(NEDGES / 256), dim3(256), 0, stream>>>(idx_t, cursor, order, flag);

  atom_pre<<<dim3((NATOMS + 63) / 64), dim3(256), 0, stream>>>(h, h_res, W);
  edge_atom<<<dim3(2048), dim3(256), 0, stream>>>(bf, h_res, idx_s, segp, order, W, x2, flag);
  atom_post<<<dim3((NATOMS + 63) / 64), dim3(256), 0, stream>>>(x2, out, W, scale);
}

// Round 3
// 356.296 us; speedup vs baseline: 1.4193x; 1.2270x over previous
//
#include <hip/hip_runtime.h>

#define EMB 128
#define NATOMS 50000
#define NEDGES 800000
#define PADN 50176            // 196 * 256 >= NATOMS

typedef __attribute__((ext_vector_type(8))) short bf16x8;
typedef __attribute__((ext_vector_type(4))) float f32x4;

// ---------- ws layout ----------
static const size_t H_RES_OFF  = 0;                                   // 25.6 MB f32
static const size_t X2_OFF     = (size_t)NATOMS * EMB * 4;            // 25.6 MB f32
static const size_t W_OFF      = 2 * (size_t)NATOMS * EMB * 4;        // 320 KB bf16
static const size_t FLAG_OFF   = W_OFF + 10 * 128 * 128 * 2;          // 4 B
static const size_t COUNTS_OFF = (FLAG_OFF + 4 + 255) & ~(size_t)255; // PADN ints
static const size_t SEG_OFF    = COUNTS_OFF + (size_t)PADN * 4;       // PADN ints
static const size_t CURSOR_OFF = SEG_OFF + (size_t)PADN * 4;          // PADN ints
static const size_t BSUM_OFF   = CURSOR_OFF + (size_t)PADN * 4;       // 256 ints
static const size_t ORDER_OFF  = BSUM_OFF + 1024;                     // NEDGES ints

__device__ __forceinline__ short f2bf(float f) {
  unsigned u = __float_as_uint(f);
  u += 0x7fffu + ((u >> 16) & 1u);   // round-to-nearest-even
  return (short)(u >> 16);
}

__device__ __forceinline__ float ssilu(float x) {
  return x * (1.0f / 0.6f) / (1.0f + __expf(-x));
}

// XOR-swizzled LDS indices: 16B units within each 128-elem row, unit ^= (row&7)
__device__ __forceinline__ int xidx(int row, int k) {   // f32 tile [rows][128]
  return (row << 7) + ((((k >> 2) ^ (row & 7)) << 2) | (k & 3));
}
__device__ __forceinline__ int bidx(int row, int k) {   // bf16 tile [rows][128]
  return (row << 7) + ((((k >> 3) ^ (row & 7)) << 3) | (k & 7));
}

// Linear 32KB global->LDS copy of one pre-swizzled weight slot.
__device__ __forceinline__ void stage_w(const short* __restrict__ src, short* dst) {
  const int wave = threadIdx.x >> 6;
  const int lane = threadIdx.x & 63;
  const char* s = (const char*)src;
  char* d = (char*)dst;
#pragma unroll
  for (int i = 0; i < 8; ++i) {
    const int off = wave * 8192 + i * 1024;
    __builtin_amdgcn_global_load_lds(
        (const __attribute__((address_space(1))) void*)(s + off + lane * 16),
        (__attribute__((address_space(3))) void*)(d + off), 16, 0, 0);
  }
}

__device__ __forceinline__ void stage_x(const float* __restrict__ src, int row0, float* x) {
#pragma unroll
  for (int i = 0; i < 8; ++i) {
    const int c = threadIdx.x + i * 256;
    const int row = c >> 5, unit = c & 31;
    f32x4 v = {0.f, 0.f, 0.f, 0.f};
    if (row0 + row < NATOMS) v = *(const f32x4*)(src + (size_t)(row0 + row) * EMB + unit * 4);
    *(f32x4*)&x[(row << 7) + ((unit ^ (row & 7)) << 2)] = v;
  }
}

template <bool SRC_BF16>
__device__ __forceinline__ void gemm_stage(const float* xsrc, const short* ysrc,
                                           const short* w, int wr0, int lr, int lh,
                                           f32x4* acc) {
#pragma unroll
  for (int kk = 0; kk < 4; ++kk) {
    const int k0 = kk * 32 + lh * 8;
    const int ra = wr0 + lr;
    bf16x8 a;
    if constexpr (SRC_BF16) {
      a = *(const bf16x8*)&ysrc[bidx(ra, k0)];
    } else {
      f32x4 u0 = *(const f32x4*)&xsrc[xidx(ra, k0)];
      f32x4 u1 = *(const f32x4*)&xsrc[xidx(ra, k0 + 4)];
      a[0] = f2bf(u0[0]); a[1] = f2bf(u0[1]); a[2] = f2bf(u0[2]); a[3] = f2bf(u0[3]);
      a[4] = f2bf(u1[0]); a[5] = f2bf(u1[1]); a[6] = f2bf(u1[2]); a[7] = f2bf(u1[3]);
    }
#pragma unroll
    for (int j0 = 0; j0 < 8; ++j0) {
      bf16x8 b = *(const bf16x8*)&w[bidx(j0 * 16 + lr, k0)];
      acc[j0] = __builtin_amdgcn_mfma_f32_16x16x32_bf16(a, b, acc[j0], 0, 0, 0);
    }
  }
}

// ---------------- K0: weight prep ----------------
__global__ void prep_weights(const float* __restrict__ wbf, const float* __restrict__ wpre,
                             const float* __restrict__ wmlp1, const float* __restrict__ wres,
                             short* __restrict__ W) {
  const int s = blockIdx.x >> 7;
  const int k = blockIdx.x & 127;
  const int n = threadIdx.x;
  const float* src;
  if (s == 0) src = wbf;
  else if (s <= 2) src = wpre + (s - 1) * 16384;
  else if (s == 3) src = wmlp1;
  else src = wres + (s - 4) * 16384;
  const float v = src[k * EMB + n];
  W[s * 16384 + (n << 7) + ((((k >> 3) ^ (n & 7)) << 3) | (k & 7))] = f2bf(v);
}

// ---------------- idx dtype detection ----------------
__global__ void detect_idx(const int* __restrict__ idx, int* __restrict__ flag) {
  const int lane = threadIdx.x & 63;
  const int v = idx[2 * lane + 1];
  const unsigned long long nz = __ballot(v != 0);
  if (lane == 0) *flag = (nz == 0ull) ? 1 : 0;   // 1 => int64
}

__device__ __forceinline__ int load_idx(const void* p, int e, int f64) {
  return f64 ? (int)((const long long*)p)[e] : ((const int*)p)[e];
}

// ---------------- sort pipeline ----------------
__global__ void hist_kernel(const void* __restrict__ idx_t_p, int* __restrict__ counts,
                            const int* __restrict__ flag) {
  const int e = blockIdx.x * 256 + threadIdx.x;
  if (e < NEDGES) atomicAdd(&counts[load_idx(idx_t_p, e, *flag)], 1);
}

__global__ void scan_blocks(const int* __restrict__ counts, int* __restrict__ seg,
                            int* __restrict__ bsum) {
  const int i = blockIdx.x * 256 + threadIdx.x;
  const int lane = threadIdx.x & 63, wave = threadIdx.x >> 6;
  const int v = counts[i];
  int incl = v;
#pragma unroll
  for (int d = 1; d < 64; d <<= 1) {
    int t = __shfl_up(incl, d, 64);
    if (lane >= d) incl += t;
  }
  __shared__ int wtot[4];
  if (lane == 63) wtot[wave] = incl;
  __syncthreads();
  int woff = 0;
  for (int w = 0; w < wave; ++w) woff += wtot[w];
  seg[i] = woff + incl - v;
  if (threadIdx.x == 255) bsum[blockIdx.x] = woff + incl;
}

__global__ void scan_top(int* __restrict__ bsum) {
  const int i = threadIdx.x;
  const int lane = i & 63, wave = i >> 6;
  const int v = (i < 196) ? bsum[i] : 0;
  int incl = v;
#pragma unroll
  for (int d = 1; d < 64; d <<= 1) {
    int t = __shfl_up(incl, d, 64);
    if (lane >= d) incl += t;
  }
  __shared__ int wtot[4];
  if (lane == 63) wtot[wave] = incl;
  __syncthreads();
  int woff = 0;
  for (int w = 0; w < wave; ++w) woff += wtot[w];
  if (i < 196) bsum[i] = woff + incl - v;
}

__global__ void add_off(int* __restrict__ seg, const int* __restrict__ bsum,
                        int* __restrict__ cursor) {
  const int i = blockIdx.x * 256 + threadIdx.x;
  const int s = seg[i] + bsum[blockIdx.x];
  seg[i] = s;
  cursor[i] = s;
}

__global__ void scatter_kernel(const void* __restrict__ idx_t_p, int* __restrict__ cursor,
                               int* __restrict__ order, const int* __restrict__ flag) {
  const int e = blockIdx.x * 256 + threadIdx.x;
  if (e < NEDGES) {
    const int t = load_idx(idx_t_p, e, *flag);
    const int pos = atomicAdd(&cursor[t], 1);
    order[pos] = e;
  }
}

// ---------------- K1: pre-residual ----------------
__global__ __launch_bounds__(256, 2) void atom_pre(const float* __restrict__ h,
                                                   float* __restrict__ h_res,
                                                   const short* __restrict__ W) {
  __shared__ float x_lds[64 * 128];
  __shared__ short y_lds[64 * 128];
  __shared__ short w_lds[128 * 128];
  const int lane = threadIdx.x & 63, wave = threadIdx.x >> 6;
  const int lr = lane & 15, lh = lane >> 4;
  const int row0 = blockIdx.x * 64, wr0 = wave * 16;
  const f32x4 vzero = {0.f, 0.f, 0.f, 0.f};

  stage_x(h, row0, x_lds);
  stage_w(W + 1 * 16384, w_lds);
  __syncthreads();

  f32x4 acc[8];
#pragma unroll
  for (int j = 0; j < 8; ++j) acc[j] = vzero;
  gemm_stage<false>(x_lds, nullptr, w_lds, wr0, lr, lh, acc);
#pragma unroll
  for (int j0 = 0; j0 < 8; ++j0)
#pragma unroll
    for (int j = 0; j < 4; ++j)
      y_lds[bidx(wr0 + lh * 4 + j, j0 * 16 + lr)] = f2bf(ssilu(acc[j0][j]));

  __syncthreads();
  stage_w(W + 2 * 16384, w_lds);
  __syncthreads();

#pragma unroll
  for (int j = 0; j < 8; ++j) acc[j] = vzero;
  gemm_stage<true>(nullptr, y_lds, w_lds, wr0, lr, lh, acc);

#pragma unroll
  for (int j = 0; j < 4; ++j) {
    const int row = wr0 + lh * 4 + j;
    const int ga = row0 + row;
    if (ga < NATOMS) {
#pragma unroll
      for (int j0 = 0; j0 < 8; ++j0) {
        const int col = j0 * 16 + lr;
        h_res[(size_t)ga * EMB + col] =
            (x_lds[xidx(row, col)] + ssilu(acc[j0][j])) * 0.70710678118654752440f;
      }
    }
  }
}

// ---------------- K2: sorted-edge GEMM + hadamard + segmented sum ----------------
// Each wave owns 32 consecutive sorted positions. Interior segments: plain store.
// Boundary-crossing segments: atomicAdd partials.
__global__ __launch_bounds__(256, 4) void edge_sorted(const float* __restrict__ bf,
                                                      const float* __restrict__ h_res,
                                                      const void* __restrict__ idx_s_p,
                                                      const void* __restrict__ idx_t_p,
                                                      const int* __restrict__ seg,
                                                      const int* __restrict__ order,
                                                      const short* __restrict__ W,
                                                      float* __restrict__ x2,
                                                      const int* __restrict__ flag) {
  __shared__ short w_lds[128 * 128];
  const int lane = threadIdx.x & 63, wave = threadIdx.x >> 6;
  const int lr = lane & 15, lh = lane >> 4;
  const int f64 = *flag;

  stage_w(W, w_lds);   // slot 0 = w_bf
  __syncthreads();

  const int p0 = blockIdx.x * 128 + wave * 32;   // wave's sorted range [p0, p0+32)
  const int r32 = lane & 31;                     // row id (dup across half-waves)
  const int e_mine = order[p0 + r32];
  const int is_mine = load_idx(idx_s_p, e_mine, f64);
  const int it_mine = load_idx(idx_t_p, e_mine, f64);

  // edge ids for this lane's A-fragment rows
  const int e_rf0 = __shfl(e_mine, lr, 64);
  const int e_rf1 = __shfl(e_mine, 16 + lr, 64);

  // ---- load + convert A fragments (32 rows x 128 k), deep MLP ----
  bf16x8 a_all[2][4];
#pragma unroll
  for (int kk = 0; kk < 4; ++kk) {
#pragma unroll
    for (int rf = 0; rf < 2; ++rf) {
      const int e = rf ? e_rf1 : e_rf0;
      const float* p = bf + (size_t)e * EMB + kk * 32 + lh * 8;
      f32x4 u0 = *(const f32x4*)p;
      f32x4 u1 = *(const f32x4*)(p + 4);
      bf16x8 a;
      a[0] = f2bf(u0[0]); a[1] = f2bf(u0[1]); a[2] = f2bf(u0[2]); a[3] = f2bf(u0[3]);
      a[4] = f2bf(u1[0]); a[5] = f2bf(u1[1]); a[6] = f2bf(u1[2]); a[7] = f2bf(u1[3]);
      a_all[rf][kk] = a;
    }
  }

  // ---- MFMA: acc[rf][j0] covers rows rf*16+4lh+j, cols j0*16+lr ----
  f32x4 acc[2][8];
  const f32x4 vzero = {0.f, 0.f, 0.f, 0.f};
#pragma unroll
  for (int rf = 0; rf < 2; ++rf)
#pragma unroll
    for (int j0 = 0; j0 < 8; ++j0) acc[rf][j0] = vzero;

#pragma unroll
  for (int kk = 0; kk < 4; ++kk) {
#pragma unroll
    for (int j0 = 0; j0 < 8; ++j0) {
      bf16x8 b = *(const bf16x8*)&w_lds[bidx(j0 * 16 + lr, kk * 32 + lh * 8)];
      acc[0][j0] = __builtin_amdgcn_mfma_f32_16x16x32_bf16(a_all[0][kk], b, acc[0][j0], 0, 0, 0);
      acc[1][j0] = __builtin_amdgcn_mfma_f32_16x16x32_bf16(a_all[1][kk], b, acc[1][j0], 0, 0, 0);
    }
  }

  // ---- Hadamard with h_res[idx_s] (in-place on acc) ----
#pragma unroll
  for (int rf = 0; rf < 2; ++rf) {
#pragma unroll
    for (int j = 0; j < 4; ++j) {
      const int isj = __shfl(is_mine, rf * 16 + 4 * lh + j, 64);
      const float* hrow = h_res + (size_t)isj * EMB;
#pragma unroll
      for (int j0 = 0; j0 < 8; ++j0)
        acc[rf][j0][j] *= hrow[j0 * 16 + lr];
    }
  }

  // ---- segmented sum over sorted rows ----
  int r = 0;
  while (r < 32) {
    const int t = __shfl(it_mine, r, 64);                       // wave-uniform target
    const unsigned long long bal = __ballot(it_mine == t);
    const unsigned long long m = (bal & 0xffffffffull) >> r;    // contiguous run from bit 0
    const int cnt = (int)__builtin_ctzll(~m);                   // run length (>=1)
    const int end = r + cnt;

    float psum[8] = {0.f, 0.f, 0.f, 0.f, 0.f, 0.f, 0.f, 0.f};
#pragma unroll
    for (int rf = 0; rf < 2; ++rf) {
#pragma unroll
      for (int j = 0; j < 4; ++j) {
        const int row = rf * 16 + 4 * lh + j;
        if (row >= r && row < end) {
#pragma unroll
          for (int j0 = 0; j0 < 8; ++j0) psum[j0] += acc[rf][j0][j];
        }
      }
    }
#pragma unroll
    for (int j0 = 0; j0 < 8; ++j0) {
      psum[j0] += __shfl_xor(psum[j0], 16, 64);
      psum[j0] += __shfl_xor(psum[j0], 32, 64);
    }

    const int s0 = seg[t], s1 = seg[t + 1];
    const bool interior = (s0 == p0 + r) && (s1 == p0 + end);
    if (lane < 16) {
      float* orow = x2 + (size_t)t * EMB;
      if (interior) {
#pragma unroll
        for (int j0 = 0; j0 < 8; ++j0) orow[j0 * 16 + lane] = psum[j0];
      } else {
#pragma unroll
        for (int j0 = 0; j0 < 8; ++j0) atomicAdd(&orow[j0 * 16 + lane], psum[j0]);
      }
    }
    r = end;
  }
}

// ---------------- K3: post MLP ----------------
__global__ __launch_bounds__(256, 2) void atom_post(const float* __restrict__ x2,
                                                    float* __restrict__ out,
                                                    const short* __restrict__ W,
                                                    const float* __restrict__ scale_sum) {
  __shared__ float x_lds[64 * 128];
  __shared__ short y_lds[64 * 128];
  __shared__ short w_lds[128 * 128];
  const int lane = threadIdx.x & 63, wave = threadIdx.x >> 6;
  const int lr = lane & 15, lh = lane >> 4;
  const int row0 = blockIdx.x * 64, wr0 = wave * 16;
  const float sc = scale_sum[0];
  const f32x4 vzero = {0.f, 0.f, 0.f, 0.f};

  stage_x(x2, row0, x_lds);
  stage_w(W + 3 * 16384, w_lds);   // w_mlp1
  __syncthreads();

  f32x4 acc[8];
#pragma unroll
  for (int j = 0; j < 8; ++j) acc[j] = vzero;
  gemm_stage<false>(x_lds, nullptr, w_lds, wr0, lr, lh, acc);
#pragma unroll
  for (int j0 = 0; j0 < 8; ++j0)
#pragma unroll
    for (int j = 0; j < 4; ++j)
      x_lds[xidx(wr0 + lh * 4 + j, j0 * 16 + lr)] = ssilu(acc[j0][j] * sc);

  for (int L = 0; L < 3; ++L) {
    __syncthreads();
    stage_w(W + (size_t)(4 + 2 * L) * 16384, w_lds);
    __syncthreads();
#pragma unroll
    for (int j = 0; j < 8; ++j) acc[j] = vzero;
    gemm_stage<false>(x_lds, nullptr, w_lds, wr0, lr, lh, acc);
#pragma unroll
    for (int j0 = 0; j0 < 8; ++j0)
#pragma unroll
      for (int j = 0; j < 4; ++j)
        y_lds[bidx(wr0 + lh * 4 + j, j0 * 16 + lr)] = f2bf(ssilu(acc[j0][j]));

    __syncthreads();
    stage_w(W + (size_t)(5 + 2 * L) * 16384, w_lds);
    __syncthreads();
#pragma unroll
    for (int j = 0; j < 8; ++j) acc[j] = vzero;
    gemm_stage<true>(nullptr, y_lds, w_lds, wr0, lr, lh, acc);

    if (L < 2) {
#pragma unroll
      for (int j = 0; j < 4; ++j) {
        const int row = wr0 + lh * 4 + j;
#pragma unroll
        for (int j0 = 0; j0 < 8; ++j0) {
          const int col = j0 * 16 + lr;
          const float xv = x_lds[xidx(row, col)];
          x_lds[xidx(row, col)] = (xv + ssilu(acc[j0][j])) * 0.70710678118654752440f;
        }
      }
    } else {
#pragma unroll
      for (int j = 0; j < 4; ++j) {
        const int row = wr0 + lh * 4 + j;
        const int ga = row0 + row;
        if (ga < NATOMS) {
#pragma unroll
          for (int j0 = 0; j0 < 8; ++j0) {
            const int col = j0 * 16 + lr;
            out[(size_t)ga * EMB + col] =
                (x_lds[xidx(row, col)] + ssilu(acc[j0][j])) * 0.70710678118654752440f;
          }
        }
      }
    }
  }
}

extern "C" void kernel_launch(void* const* d_in, const int* in_sizes, int n_in,
                              void* d_out, int out_size, void* d_ws, size_t ws_size,
                              hipStream_t stream) {
  const float* h      = (const float*)d_in[0];
  const float* bf     = (const float*)d_in[1];
  const void*  idx_s  = d_in[2];
  const void*  idx_t  = d_in[3];
  const float* w_bf   = (const float*)d_in[4];
  const float* w_pre  = (const float*)d_in[5];
  const float* w_mlp1 = (const float*)d_in[6];
  const float* w_res  = (const float*)d_in[7];
  const float* scale  = (const float*)d_in[8];
  float* out = (float*)d_out;

  char* ws = (char*)d_ws;
  float* h_res  = (float*)(ws + H_RES_OFF);
  float* x2     = (float*)(ws + X2_OFF);
  short* W      = (short*)(ws + W_OFF);
  int*   flag   = (int*)(ws + FLAG_OFF);
  int*   counts = (int*)(ws + COUNTS_OFF);
  int*   segp   = (int*)(ws + SEG_OFF);
  int*   cursor = (int*)(ws + CURSOR_OFF);
  int*   bsum   = (int*)(ws + BSUM_OFF);
  int*   order  = (int*)(ws + ORDER_OFF);

  hipMemsetAsync(counts, 0, (size_t)PADN * 4, stream);
  hipMemsetAsync(x2, 0, (size_t)NATOMS * EMB * 4, stream);
  prep_weights<<<dim3(10 * 128), dim3(128), 0, stream>>>(w_bf, w_pre, w_mlp1, w_res, W);
  detect_idx<<<dim3(1), dim3(64), 0, stream>>>((const int*)idx_s, flag);

  hist_kernel<<<dim3(NEDGES / 256), dim3(256), 0, stream>>>(idx_t, counts, flag);
  scan_blocks<<<dim3(PADN / 256), dim3(256), 0, stream>>>(counts, segp, bsum);
  scan_top<<<dim3(1), dim3(256), 0, stream>>>(bsum);
  add_off<<<dim3(PADN / 256), dim3(256), 0, stream>>>(segp, bsum, cursor);
  scatter_kernel<<<dim3(NEDGES / 256), dim3(256), 0, stream>>>(idx_t, cursor, order, flag);

  atom_pre<<<dim3((NATOMS + 63) / 64), dim3(256), 0, stream>>>(h, h_res, W);
  edge_sorted<<<dim3(NEDGES / 128), dim3(256), 0, stream>>>(bf, h_res, idx_s, idx_t, segp,
                                                            order, W, x2, flag);
  atom_post<<<dim3((NATOMS + 63) / 64), dim3(256), 0, stream>>>(x2, out, W, scale);
}

// Round 4
// 354.912 us; speedup vs baseline: 1.4248x; 1.0039x over previous
//
#include <hip/hip_runtime.h>

#define EMB 128
#define NATOMS 50000
#define NEDGES 800000
#define PADN 50176            // 196 * 256 >= NATOMS

typedef __attribute__((ext_vector_type(8))) short bf16x8;
typedef __attribute__((ext_vector_type(4))) float f32x4;

// ---------- ws layout ----------
static const size_t H_RES_OFF  = 0;                                   // 25.6 MB f32
static const size_t X2_OFF     = (size_t)NATOMS * EMB * 4;            // 25.6 MB f32
static const size_t W_OFF      = 2 * (size_t)NATOMS * EMB * 4;        // 320 KB bf16
static const size_t FLAG_OFF   = W_OFF + 10 * 128 * 128 * 2;          // 4 B
static const size_t COUNTS_OFF = (FLAG_OFF + 4 + 255) & ~(size_t)255; // PADN ints
static const size_t SEG_OFF    = COUNTS_OFF + (size_t)PADN * 4;       // PADN ints
static const size_t CURSOR_OFF = SEG_OFF + (size_t)PADN * 4;          // PADN ints
static const size_t BSUM_OFF   = CURSOR_OFF + (size_t)PADN * 4;       // 256 ints
static const size_t ORDER_OFF  = BSUM_OFF + 1024;                     // NEDGES ints

__device__ __forceinline__ short f2bf(float f) {
  unsigned u = __float_as_uint(f);
  u += 0x7fffu + ((u >> 16) & 1u);   // round-to-nearest-even
  return (short)(u >> 16);
}

__device__ __forceinline__ float ssilu(float x) {
  return x * (1.0f / 0.6f) / (1.0f + __expf(-x));
}

// XOR-swizzled LDS indices: 16B units within each 128-elem row, unit ^= (row&7)
__device__ __forceinline__ int xidx(int row, int k) {   // f32 tile [rows][128]
  return (row << 7) + ((((k >> 2) ^ (row & 7)) << 2) | (k & 3));
}
__device__ __forceinline__ int bidx(int row, int k) {   // bf16 tile [rows][128]
  return (row << 7) + ((((k >> 3) ^ (row & 7)) << 3) | (k & 7));
}

// Linear 32KB global->LDS copy of one pre-swizzled weight slot.
__device__ __forceinline__ void stage_w(const short* __restrict__ src, short* dst) {
  const int wave = threadIdx.x >> 6;
  const int lane = threadIdx.x & 63;
  const char* s = (const char*)src;
  char* d = (char*)dst;
#pragma unroll
  for (int i = 0; i < 8; ++i) {
    const int off = wave * 8192 + i * 1024;
    __builtin_amdgcn_global_load_lds(
        (const __attribute__((address_space(1))) void*)(s + off + lane * 16),
        (__attribute__((address_space(3))) void*)(d + off), 16, 0, 0);
  }
}

__device__ __forceinline__ void stage_x(const float* __restrict__ src, int row0, float* x) {
#pragma unroll
  for (int i = 0; i < 8; ++i) {
    const int c = threadIdx.x + i * 256;
    const int row = c >> 5, unit = c & 31;
    f32x4 v = {0.f, 0.f, 0.f, 0.f};
    if (row0 + row < NATOMS) v = *(const f32x4*)(src + (size_t)(row0 + row) * EMB + unit * 4);
    *(f32x4*)&x[(row << 7) + ((unit ^ (row & 7)) << 2)] = v;
  }
}

template <bool SRC_BF16>
__device__ __forceinline__ void gemm_stage(const float* xsrc, const short* ysrc,
                                           const short* w, int wr0, int lr, int lh,
                                           f32x4* acc) {
#pragma unroll
  for (int kk = 0; kk < 4; ++kk) {
    const int k0 = kk * 32 + lh * 8;
    const int ra = wr0 + lr;
    bf16x8 a;
    if constexpr (SRC_BF16) {
      a = *(const bf16x8*)&ysrc[bidx(ra, k0)];
    } else {
      f32x4 u0 = *(const f32x4*)&xsrc[xidx(ra, k0)];
      f32x4 u1 = *(const f32x4*)&xsrc[xidx(ra, k0 + 4)];
      a[0] = f2bf(u0[0]); a[1] = f2bf(u0[1]); a[2] = f2bf(u0[2]); a[3] = f2bf(u0[3]);
      a[4] = f2bf(u1[0]); a[5] = f2bf(u1[1]); a[6] = f2bf(u1[2]); a[7] = f2bf(u1[3]);
    }
#pragma unroll
    for (int j0 = 0; j0 < 8; ++j0) {
      bf16x8 b = *(const bf16x8*)&w[bidx(j0 * 16 + lr, k0)];
      acc[j0] = __builtin_amdgcn_mfma_f32_16x16x32_bf16(a, b, acc[j0], 0, 0, 0);
    }
  }
}

// ---------------- K0: weight prep ----------------
__global__ void prep_weights(const float* __restrict__ wbf, const float* __restrict__ wpre,
                             const float* __restrict__ wmlp1, const float* __restrict__ wres,
                             short* __restrict__ W) {
  const int s = blockIdx.x >> 7;
  const int k = blockIdx.x & 127;
  const int n = threadIdx.x;
  const float* src;
  if (s == 0) src = wbf;
  else if (s <= 2) src = wpre + (s - 1) * 16384;
  else if (s == 3) src = wmlp1;
  else src = wres + (s - 4) * 16384;
  const float v = src[k * EMB + n];
  W[s * 16384 + (n << 7) + ((((k >> 3) ^ (n & 7)) << 3) | (k & 7))] = f2bf(v);
}

// ---------------- idx dtype detection ----------------
__global__ void detect_idx(const int* __restrict__ idx, int* __restrict__ flag) {
  const int lane = threadIdx.x & 63;
  const int v = idx[2 * lane + 1];
  const unsigned long long nz = __ballot(v != 0);
  if (lane == 0) *flag = (nz == 0ull) ? 1 : 0;   // 1 => int64
}

__device__ __forceinline__ int load_idx(const void* p, int e, int f64) {
  return f64 ? (int)((const long long*)p)[e] : ((const int*)p)[e];
}

// ---------------- sort pipeline ----------------
__global__ void hist_kernel(const void* __restrict__ idx_t_p, int* __restrict__ counts,
                            const int* __restrict__ flag) {
  const int e = blockIdx.x * 256 + threadIdx.x;
  if (e < NEDGES) atomicAdd(&counts[load_idx(idx_t_p, e, *flag)], 1);
}

__global__ void scan_blocks(const int* __restrict__ counts, int* __restrict__ seg,
                            int* __restrict__ bsum) {
  const int i = blockIdx.x * 256 + threadIdx.x;
  const int lane = threadIdx.x & 63, wave = threadIdx.x >> 6;
  const int v = counts[i];
  int incl = v;
#pragma unroll
  for (int d = 1; d < 64; d <<= 1) {
    int t = __shfl_up(incl, d, 64);
    if (lane >= d) incl += t;
  }
  __shared__ int wtot[4];
  if (lane == 63) wtot[wave] = incl;
  __syncthreads();
  int woff = 0;
  for (int w = 0; w < wave; ++w) woff += wtot[w];
  seg[i] = woff + incl - v;
  if (threadIdx.x == 255) bsum[blockIdx.x] = woff + incl;
}

__global__ void scan_top(int* __restrict__ bsum) {
  const int i = threadIdx.x;
  const int lane = i & 63, wave = i >> 6;
  const int v = (i < 196) ? bsum[i] : 0;
  int incl = v;
#pragma unroll
  for (int d = 1; d < 64; d <<= 1) {
    int t = __shfl_up(incl, d, 64);
    if (lane >= d) incl += t;
  }
  __shared__ int wtot[4];
  if (lane == 63) wtot[wave] = incl;
  __syncthreads();
  int woff = 0;
  for (int w = 0; w < wave; ++w) woff += wtot[w];
  if (i < 196) bsum[i] = woff + incl - v;
}

__global__ void add_off(int* __restrict__ seg, const int* __restrict__ bsum,
                        int* __restrict__ cursor) {
  const int i = blockIdx.x * 256 + threadIdx.x;
  const int s = seg[i] + bsum[blockIdx.x];
  seg[i] = s;
  cursor[i] = s;
}

__global__ void scatter_kernel(const void* __restrict__ idx_t_p, int* __restrict__ cursor,
                               int* __restrict__ order, const int* __restrict__ flag) {
  const int e = blockIdx.x * 256 + threadIdx.x;
  if (e < NEDGES) {
    const int t = load_idx(idx_t_p, e, *flag);
    const int pos = atomicAdd(&cursor[t], 1);
    order[pos] = e;
  }
}

// ---------------- K1: pre-residual ----------------
__global__ __launch_bounds__(256, 2) void atom_pre(const float* __restrict__ h,
                                                   float* __restrict__ h_res,
                                                   const short* __restrict__ W) {
  __shared__ float x_lds[64 * 128];
  __shared__ short y_lds[64 * 128];
  __shared__ short w_lds[128 * 128];
  const int lane = threadIdx.x & 63, wave = threadIdx.x >> 6;
  const int lr = lane & 15, lh = lane >> 4;
  const int row0 = blockIdx.x * 64, wr0 = wave * 16;
  const f32x4 vzero = {0.f, 0.f, 0.f, 0.f};

  stage_x(h, row0, x_lds);
  stage_w(W + 1 * 16384, w_lds);
  __syncthreads();

  f32x4 acc[8];
#pragma unroll
  for (int j = 0; j < 8; ++j) acc[j] = vzero;
  gemm_stage<false>(x_lds, nullptr, w_lds, wr0, lr, lh, acc);
#pragma unroll
  for (int j0 = 0; j0 < 8; ++j0)
#pragma unroll
    for (int j = 0; j < 4; ++j)
      y_lds[bidx(wr0 + lh * 4 + j, j0 * 16 + lr)] = f2bf(ssilu(acc[j0][j]));

  __syncthreads();
  stage_w(W + 2 * 16384, w_lds);
  __syncthreads();

#pragma unroll
  for (int j = 0; j < 8; ++j) acc[j] = vzero;
  gemm_stage<true>(nullptr, y_lds, w_lds, wr0, lr, lh, acc);

#pragma unroll
  for (int j = 0; j < 4; ++j) {
    const int row = wr0 + lh * 4 + j;
    const int ga = row0 + row;
    if (ga < NATOMS) {
#pragma unroll
      for (int j0 = 0; j0 < 8; ++j0) {
        const int col = j0 * 16 + lr;
        h_res[(size_t)ga * EMB + col] =
            (x_lds[xidx(row, col)] + ssilu(acc[j0][j])) * 0.70710678118654752440f;
      }
    }
  }
}

// ---------------- K2: sorted-edge GEMM + hadamard + segmented sum ----------------
// Each wave owns 32 consecutive sorted positions. Interior segments: plain store.
// Boundary-crossing segments: atomicAdd partials.
__global__ __launch_bounds__(256, 4) void edge_sorted(const float* __restrict__ bf,
                                                      const float* __restrict__ h_res,
                                                      const void* __restrict__ idx_s_p,
                                                      const void* __restrict__ idx_t_p,
                                                      const int* __restrict__ seg,
                                                      const int* __restrict__ order,
                                                      const short* __restrict__ W,
                                                      float* __restrict__ x2,
                                                      const int* __restrict__ flag) {
  __shared__ short w_lds[128 * 128];
  const int lane = threadIdx.x & 63, wave = threadIdx.x >> 6;
  const int lr = lane & 15, lh = lane >> 4;
  const int f64 = *flag;

  stage_w(W, w_lds);   // slot 0 = w_bf
  __syncthreads();

  const int p0 = blockIdx.x * 128 + wave * 32;   // wave's sorted range [p0, p0+32)
  const int r32 = lane & 31;                     // row id (dup across half-waves)
  const int e_mine = order[p0 + r32];
  const int is_mine = load_idx(idx_s_p, e_mine, f64);
  const int it_mine = load_idx(idx_t_p, e_mine, f64);

  // edge ids for this lane's A-fragment rows
  const int e_rf0 = __shfl(e_mine, lr, 64);
  const int e_rf1 = __shfl(e_mine, 16 + lr, 64);

  // ---- load + convert A fragments (32 rows x 128 k), deep MLP ----
  bf16x8 a_all[2][4];
#pragma unroll
  for (int kk = 0; kk < 4; ++kk) {
#pragma unroll
    for (int rf = 0; rf < 2; ++rf) {
      const int e = rf ? e_rf1 : e_rf0;
      const float* p = bf + (size_t)e * EMB + kk * 32 + lh * 8;
      f32x4 u0 = *(const f32x4*)p;
      f32x4 u1 = *(const f32x4*)(p + 4);
      bf16x8 a;
      a[0] = f2bf(u0[0]); a[1] = f2bf(u0[1]); a[2] = f2bf(u0[2]); a[3] = f2bf(u0[3]);
      a[4] = f2bf(u1[0]); a[5] = f2bf(u1[1]); a[6] = f2bf(u1[2]); a[7] = f2bf(u1[3]);
      a_all[rf][kk] = a;
    }
  }

  // ---- MFMA: acc[rf][j0] covers rows rf*16+4lh+j, cols j0*16+lr ----
  f32x4 acc[2][8];
  const f32x4 vzero = {0.f, 0.f, 0.f, 0.f};
#pragma unroll
  for (int rf = 0; rf < 2; ++rf)
#pragma unroll
    for (int j0 = 0; j0 < 8; ++j0) acc[rf][j0] = vzero;

#pragma unroll
  for (int kk = 0; kk < 4; ++kk) {
#pragma unroll
    for (int j0 = 0; j0 < 8; ++j0) {
      bf16x8 b = *(const bf16x8*)&w_lds[bidx(j0 * 16 + lr, kk * 32 + lh * 8)];
      acc[0][j0] = __builtin_amdgcn_mfma_f32_16x16x32_bf16(a_all[0][kk], b, acc[0][j0], 0, 0, 0);
      acc[1][j0] = __builtin_amdgcn_mfma_f32_16x16x32_bf16(a_all[1][kk], b, acc[1][j0], 0, 0, 0);
    }
  }

  // ---- Hadamard with h_res[idx_s] (in-place on acc) ----
#pragma unroll
  for (int rf = 0; rf < 2; ++rf) {
#pragma unroll
    for (int j = 0; j < 4; ++j) {
      const int isj = __shfl(is_mine, rf * 16 + 4 * lh + j, 64);
      const float* hrow = h_res + (size_t)isj * EMB;
#pragma unroll
      for (int j0 = 0; j0 < 8; ++j0)
        acc[rf][j0][j] *= hrow[j0 * 16 + lr];
    }
  }

  // ---- segmented sum over sorted rows ----
  int r = 0;
  while (r < 32) {
    const int t = __shfl(it_mine, r, 64);                       // wave-uniform target
    const unsigned long long bal = __ballot(it_mine == t);
    const unsigned long long m = (bal & 0xffffffffull) >> r;    // contiguous run from bit 0
    const int cnt = (int)__builtin_ctzll(~m);                   // run length (>=1)
    const int end = r + cnt;

    float psum[8] = {0.f, 0.f, 0.f, 0.f, 0.f, 0.f, 0.f, 0.f};
#pragma unroll
    for (int rf = 0; rf < 2; ++rf) {
#pragma unroll
      for (int j = 0; j < 4; ++j) {
        const int row = rf * 16 + 4 * lh + j;
        if (row >= r && row < end) {
#pragma unroll
          for (int j0 = 0; j0 < 8; ++j0) psum[j0] += acc[rf][j0][j];
        }
      }
    }
#pragma unroll
    for (int j0 = 0; j0 < 8; ++j0) {
      psum[j0] += __shfl_xor(psum[j0], 16, 64);
      psum[j0] += __shfl_xor(psum[j0], 32, 64);
    }

    const int s0 = seg[t], s1 = seg[t + 1];
    const bool interior = (s0 == p0 + r) && (s1 == p0 + end);
    if (lane < 16) {
      float* orow = x2 + (size_t)t * EMB;
      if (interior) {
#pragma unroll
        for (int j0 = 0; j0 < 8; ++j0) orow[j0 * 16 + lane] = psum[j0];
      } else {
#pragma unroll
        for (int j0 = 0; j0 < 8; ++j0) atomicAdd(&orow[j0 * 16 + lane], psum[j0]);
      }
    }
    r = end;
  }
}

// ---------------- K3: post MLP ----------------
__global__ __launch_bounds__(256, 2) void atom_post(const float* __restrict__ x2,
                                                    float* __restrict__ out,
                                                    const short* __restrict__ W,
                                                    const float* __restrict__ scale_sum) {
  __shared__ float x_lds[64 * 128];
  __shared__ short y_lds[64 * 128];
  __shared__ short w_lds[128 * 128];
  const int lane = threadIdx.x & 63, wave = threadIdx.x >> 6;
  const int lr = lane & 15, lh = lane >> 4;
  const int row0 = blockIdx.x * 64, wr0 = wave * 16;
  const float sc = scale_sum[0];
  const f32x4 vzero = {0.f, 0.f, 0.f, 0.f};

  stage_x(x2, row0, x_lds);
  stage_w(W + 3 * 16384, w_lds);   // w_mlp1
  __syncthreads();

  f32x4 acc[8];
#pragma unroll
  for (int j = 0; j < 8; ++j) acc[j] = vzero;
  gemm_stage<false>(x_lds, nullptr, w_lds, wr0, lr, lh, acc);
#pragma unroll
  for (int j0 = 0; j0 < 8; ++j0)
#pragma unroll
    for (int j = 0; j < 4; ++j)
      x_lds[xidx(wr0 + lh * 4 + j, j0 * 16 + lr)] = ssilu(acc[j0][j] * sc);

  for (int L = 0; L < 3; ++L) {
    __syncthreads();
    stage_w(W + (size_t)(4 + 2 * L) * 16384, w_lds);
    __syncthreads();
#pragma unroll
    for (int j = 0; j < 8; ++j) acc[j] = vzero;
    gemm_stage<false>(x_lds, nullptr, w_lds, wr0, lr, lh, acc);
#pragma unroll
    for (int j0 = 0; j0 < 8; ++j0)
#pragma unroll
      for (int j = 0; j < 4; ++j)
        y_lds[bidx(wr0 + lh * 4 + j, j0 * 16 + lr)] = f2bf(ssilu(acc[j0][j]));

    __syncthreads();
    stage_w(W + (size_t)(5 + 2 * L) * 16384, w_lds);
    __syncthreads();
#pragma unroll
    for (int j = 0; j < 8; ++j) acc[j] = vzero;
    gemm_stage<true>(nullptr, y_lds, w_lds, wr0, lr, lh, acc);

    if (L < 2) {
#pragma unroll
      for (int j = 0; j < 4; ++j) {
        const int row = wr0 + lh * 4 + j;
#pragma unroll
        for (int j0 = 0; j0 < 8; ++j0) {
          const int col = j0 * 16 + lr;
          const float xv = x_lds[xidx(row, col)];
          x_lds[xidx(row, col)] = (xv + ssilu(acc[j0][j])) * 0.70710678118654752440f;
        }
      }
    } else {
#pragma unroll
      for (int j = 0; j < 4; ++j) {
        const int row = wr0 + lh * 4 + j;
        const int ga = row0 + row;
        if (ga < NATOMS) {
#pragma unroll
          for (int j0 = 0; j0 < 8; ++j0) {
            const int col = j0 * 16 + lr;
            out[(size_t)ga * EMB + col] =
                (x_lds[xidx(row, col)] + ssilu(acc[j0][j])) * 0.70710678118654752440f;
          }
        }
      }
    }
  }
}

extern "C" void kernel_launch(void* const* d_in, const int* in_sizes, int n_in,
                              void* d_out, int out_size, void* d_ws, size_t ws_size,
                              hipStream_t stream) {
  const float* h      = (const float*)d_in[0];
  const float* bf     = (const float*)d_in[1];
  const void*  idx_s  = d_in[2];
  const void*  idx_t  = d_in[3];
  const float* w_bf   = (const float*)d_in[4];
  const float* w_pre  = (const float*)d_in[5];
  const float* w_mlp1 = (const float*)d_in[6];
  const float* w_res  = (const float*)d_in[7];
  const float* scale  = (const float*)d_in[8];
  float* out = (float*)d_out;

  char* ws = (char*)d_ws;
  float* h_res  = (float*)(ws + H_RES_OFF);
  float* x2     = (float*)(ws + X2_OFF);
  short* W      = (short*)(ws + W_OFF);
  int*   flag   = (int*)(ws + FLAG_OFF);
  int*   counts = (int*)(ws + COUNTS_OFF);
  int*   segp   = (int*)(ws + SEG_OFF);
  int*   cursor = (int*)(ws + CURSOR_OFF);
  int*   bsum   = (int*)(ws + BSUM_OFF);
  int*   order  = (int*)(ws + ORDER_OFF);

  hipMemsetAsync(counts, 0, (size_t)PADN * 4, stream);
  hipMemsetAsync(x2, 0, (size_t)NATOMS * EMB * 4, stream);
  prep_weights<<<dim3(10 * 128), dim3(128), 0, stream>>>(w_bf, w_pre, w_mlp1, w_res, W);
  detect_idx<<<dim3(1), dim3(64), 0, stream>>>((const int*)idx_s, flag);

  hist_kernel<<<dim3(NEDGES / 256), dim3(256), 0, stream>>>(idx_t, counts, flag);
  scan_blocks<<<dim3(PADN / 256), dim3(256), 0, stream>>>(counts, segp, bsum);
  scan_top<<<dim3(1), dim3(256), 0, stream>>>(bsum);
  add_off<<<dim3(PADN / 256), dim3(256), 0, stream>>>(segp, bsum, cursor);
  scatter_kernel<<<dim3(NEDGES / 256), dim3(256), 0, stream>>>(idx_t, cursor, order, flag);

  atom_pre<<<dim3((NATOMS + 63) / 64), dim3(256), 0, stream>>>(h, h_res, W);
  edge_sorted<<<dim3(NEDGES / 128), dim3(256), 0, stream>>>(bf, h_res, idx_s, idx_t, segp,
                                                            order, W, x2, flag);
  atom_post<<<dim3((NATOMS + 63) / 64), dim3(256), 0, stream>>>(x2, out, W, scale);
}